// Round 5
// baseline (521.626 us; speedup 1.0000x reference)
//
#include <hip/hip_runtime.h>
#include <math.h>

#define BATCH 8
#define TPH   512
#define TMEL  4096
#define HCH   256
#define WLEN  256
#define KKTOT 1280

// ws offsets (in doubles)
#define OFF_WT1 0          // 1280*256
#define OFF_WT2 327680     // 1280*256
#define OFF_H1  655360     // 4096*256
#define OFF_H2  1703936    // 4096*256
#define OFF_M   2752512    // 4096
#define OFF_CEN 2756608    // 4096
#define OFF_GVH 2760704    // 257

// ---- wave (64-lane) reduction helpers ----
__device__ __forceinline__ double wsum_d(double v) {
#pragma unroll
    for (int o = 32; o > 0; o >>= 1) v += __shfl_xor(v, o);
    return v;
}
__device__ __forceinline__ float wmax_f(float v) {
#pragma unroll
    for (int o = 32; o > 0; o >>= 1) v = fmaxf(v, __shfl_xor(v, o));
    return v;
}

// transpose weights (O,I,K) -> (k*256+i, o), f32 -> f64
__global__ __launch_bounds__(256) void k_transpose_w(const float* __restrict__ w1,
                                                     const float* __restrict__ w2,
                                                     double* __restrict__ wt1,
                                                     double* __restrict__ wt2) {
    int idx = blockIdx.x;
    const float* src; double* dst; int kk;
    if (idx < KKTOT) { src = w1; dst = wt1; kk = idx; }
    else             { src = w2; dst = wt2; kk = idx - KKTOT; }
    int k = kk >> 8, i = kk & 255, o = threadIdx.x;
    dst[kk * HCH + o] = (double)src[o * KKTOT + i * 5 + k];
}

// f64 conv-as-GEMM, split-K x4 (f64 atomicAdd combine into zeroed out).
// grid (4 c-tiles, 64 m-tiles, 4 K-quarters) = 1024 blocks -> 4 blocks/CU.
// 64x64 tile, 4x4 micro, double-buffered LDS, bank-conflict-mitigated layout:
//   As stride 66 (even -> aligned double2 reads, odd-ish write spread)
//   Bs +2-double skew per 16-col group -> 2-way (free) read pattern
template <typename TS>
__global__ __launch_bounds__(256, 4) void k_conv_gemm(const TS* __restrict__ src,
                                                      const float* __restrict__ mask,
                                                      const double* __restrict__ wT,
                                                      double* __restrict__ out) {
    __shared__ double As[2][16][66];
    __shared__ double Bs[2][16][70];
    int tid = threadIdx.x;
    int ty4 = (tid >> 4) * 4, tx4 = (tid & 15) * 4;
    int c0 = blockIdx.x * 64;
    int m0 = blockIdx.y * 64;
    int kb0 = blockIdx.z * 320;
    const int NT = 20;

    // staging assignments
    int q4 = (tid & 3) * 4;      // A: k-quad within tile
    int m_l = tid >> 2;          // A: row 0..63
    int cB = tid & 63;           // B: col
    int kB0 = tid >> 6;          // B: k base (0..3), rows kB0+4j
    int pcB = cB + 2 * (cB >> 4);        // skewed B store col
    int ptx = tx4 + 2 * (tx4 >> 4);      // skewed B read col (group-contiguous)

    double acc[4][4];
#pragma unroll
    for (int i = 0; i < 4; i++)
#pragma unroll
        for (int j = 0; j < 4; j++) acc[i][j] = 0.0;

    int m = m0 + m_l;
    int mbase = m & ~511, mt = m & 511;

    double av[4], bv[4];

    auto fetch = [&](int kt) {
        int kb = kb0 + kt * 16;
        int kk = kb + q4;
        int k5 = kk >> 8, ci0 = kk & 255;
        int tt = mt + k5 - 2;
        if ((unsigned)tt < 512u) {
            int r = mbase + tt;
            double mk = (double)mask[r];
            const TS* sp = src + (size_t)r * HCH + ci0;
#pragma unroll
            for (int j = 0; j < 4; j++) av[j] = (double)sp[j] * mk;
        } else {
#pragma unroll
            for (int j = 0; j < 4; j++) av[j] = 0.0;
        }
        const double* wp = wT + (size_t)(kb + kB0) * HCH + c0 + cB;
#pragma unroll
        for (int j = 0; j < 4; j++) bv[j] = wp[(size_t)(j * 4) * HCH];
    };
    auto store = [&](int bf) {
#pragma unroll
        for (int j = 0; j < 4; j++) As[bf][(q4 & 15) + j][m_l] = av[j];
#pragma unroll
        for (int j = 0; j < 4; j++) Bs[bf][kB0 + j * 4][pcB] = bv[j];
    };

    fetch(0);
    store(0);
    __syncthreads();
    int buf = 0;
    for (int kt = 0; kt < NT; kt++) {
        if (kt + 1 < NT) fetch(kt + 1);
#pragma unroll
        for (int k = 0; k < 16; k++) {
            const double2* Ap = (const double2*)&As[buf][k][ty4];
            const double2* Bp = (const double2*)&Bs[buf][k][ptx];
            double2 a01 = Ap[0], a23 = Ap[1];
            double2 b01 = Bp[0], b23 = Bp[1];
            double a[4] = {a01.x, a01.y, a23.x, a23.y};
            double bb[4] = {b01.x, b01.y, b23.x, b23.y};
#pragma unroll
            for (int i = 0; i < 4; i++)
#pragma unroll
                for (int j = 0; j < 4; j++) acc[i][j] += a[i] * bb[j];
        }
        if (kt + 1 < NT) store(buf ^ 1);
        __syncthreads();
        buf ^= 1;
    }
#pragma unroll
    for (int r = 0; r < 4; r++) {
        double* op = out + (size_t)(m0 + ty4 + r) * HCH + c0 + tx4;
#pragma unroll
        for (int j = 0; j < 4; j++) atomicAdd(&op[j], acc[r][j]);
    }
}

// f64: v = y + bias; channel-LN over 256 (shuffle reductions); relu. In-place OK.
__global__ __launch_bounds__(256) void k_ln_relu(const double* __restrict__ y,
                                                 const float* __restrict__ bias,
                                                 const float* __restrict__ g,
                                                 const float* __restrict__ b,
                                                 double* __restrict__ out) {
    __shared__ double part[4];
    __shared__ double bc;
    int row = blockIdx.x, tid = threadIdx.x;
    int lane = tid & 63, wid = tid >> 6;
    double v = y[row * HCH + tid] + (double)bias[tid];
    double s = wsum_d(v);
    if (lane == 0) part[wid] = s;
    __syncthreads();
    if (tid == 0) bc = (part[0] + part[1] + part[2] + part[3]) * (1.0 / 256.0);
    __syncthreads();
    double mu = bc;
    double w = v - mu;
    s = wsum_d(w * w);
    if (lane == 0) part[wid] = s;
    __syncthreads();
    if (tid == 0) bc = (part[0] + part[1] + part[2] + part[3]) * (1.0 / 256.0);
    __syncthreads();
    double var = bc;
    double o = w * (1.0 / sqrt(var + 1e-4)) * (double)g[tid] + (double)b[tid];
    out[row * HCH + tid] = fmax(o, 0.0);
}

// gvh[i] = sum_c gw[c]*projw[c,i] (f64);  gvh[256] = sum_c gw[c]*projb[c]
__global__ __launch_bounds__(256) void k_gvh(const float* __restrict__ gw,
                                             const float* __restrict__ projw,
                                             const float* __restrict__ projb,
                                             double* __restrict__ gvh) {
    __shared__ double part[4];
    int i = threadIdx.x;
    int lane = i & 63, wid = i >> 6;
    double a0 = 0.0, a1 = 0.0, a2 = 0.0, a3 = 0.0;
    for (int c = 0; c < HCH; c += 4) {
        a0 += (double)gw[c + 0] * (double)projw[(c + 0) * HCH + i];
        a1 += (double)gw[c + 1] * (double)projw[(c + 1) * HCH + i];
        a2 += (double)gw[c + 2] * (double)projw[(c + 2) * HCH + i];
        a3 += (double)gw[c + 3] * (double)projw[(c + 3) * HCH + i];
    }
    gvh[i] = ((a0 + a1) + (a2 + a3));
    double s = wsum_d((double)gw[i] * (double)projb[i]);
    if (lane == 0) part[wid] = s;
    __syncthreads();
    if (i == 0) gvh[256] = part[0] + part[1] + part[2] + part[3];
}

// m[row] = (relu(mask*(<gw,x> + <gvh,h2> + gpb) + gb0) + 1) * mask   (one wave/row)
__global__ __launch_bounds__(256) void k_m2(const float* __restrict__ x,
                                            const double* __restrict__ h2,
                                            const float* __restrict__ gw,
                                            const double* __restrict__ gvh,
                                            const float* __restrict__ gb,
                                            const float* __restrict__ mask,
                                            double* __restrict__ mbuf) {
    int lane = threadIdx.x & 63;
    int row = blockIdx.x * 4 + (threadIdx.x >> 6);
    double acc = 0.0;
#pragma unroll
    for (int j = 0; j < 4; j++) {
        int c = j * 64 + lane;
        acc += (double)gw[c] * (double)x[row * HCH + c];
        acc += gvh[c] * h2[row * HCH + c];
    }
    acc = wsum_d(acc);
    if (lane == 0) {
        double mk = (double)mask[row];
        double g0 = mk * (acc + gvh[256]) + (double)gb[0];
        mbuf[row] = (fmax(g0, 0.0) + 1.0) * mk;
    }
}

// per-batch f64: deterministic dur scatter, mel counts, scale, sequential cumsum
__global__ __launch_bounds__(512) void k_dur(const double* __restrict__ mbuf,
                                             const int* __restrict__ x2w,
                                             const int* __restrict__ m2w,
                                             double* __restrict__ center,
                                             float* __restrict__ out_mword) {
    __shared__ double ms[512];
    __shared__ int xw[512];
    __shared__ double dur[257];
    __shared__ int cntw[257];
    __shared__ double msc[512], cbuf[512];
    int b = blockIdx.x, tid = threadIdx.x;
    if (tid < 257) cntw[tid] = 0;
    ms[tid] = mbuf[b * TPH + tid];
    {
        int w = x2w[b * TPH + tid];
        xw[tid] = max(0, min(256, w));
    }
    __syncthreads();
    for (int j = 0; j < TMEL / 512; j++) {
        int ww = m2w[b * TMEL + tid + j * 512];
        ww = max(0, min(256, ww));
        atomicAdd(&cntw[ww], 1);
    }
    __syncthreads();
    if (tid >= 1 && tid <= 256) {
        double s = 0.0;
        for (int t = 0; t < TPH; t++) {
            if (xw[t] == tid) s += ms[t];
        }
        dur[tid] = s;
        out_mword[b * WLEN + tid - 1] = (float)s;
    }
    __syncthreads();
    {
        int w = xw[tid];
        double sc = (double)cntw[w] / (dur[w] + 1e-4);
        msc[tid] = ms[tid] + (sc - 1.0) * ms[tid];
    }
    __syncthreads();
    if (tid == 0) {
        double run = 0.0;
        for (int t = 0; t < TPH; t++) {
            run += msc[t];
            cbuf[t] = run - msc[t] * 0.5;
        }
    }
    __syncthreads();
    center[b * TPH + tid] = cbuf[tid];
}

// one WAVE per (b, mel) row: f64 logits, f32 cast at softmax input (the reference's
// astype), shuffle-only reductions (no LDS, no barriers), ballot-driven sparse attn.
__global__ __launch_bounds__(256) void k_attn(const float* __restrict__ x,
                                              const double* __restrict__ center,
                                              const int* __restrict__ x2w,
                                              const int* __restrict__ m2w,
                                              const float* __restrict__ mask,
                                              float* __restrict__ outA,
                                              float* __restrict__ outW) {
    int lane = threadIdx.x & 63, wid = threadIdx.x >> 6;
    int r = blockIdx.x * 4 + wid;              // r = b*4096 + mm
    int b = r >> 12;
    const double* cen = center + b * TPH;
    const int* xw = x2w + b * TPH;
    const float* mk = mask + b * TPH;
    int wv = m2w[r];
    double ym = (wv > 0) ? 1.0 : 0.0;
    double posd = (double)(r & 4095);
    float ev[8];
    float lmax = -3.0e38f;
#pragma unroll
    for (int j = 0; j < 8; j++) {
        int t = j * 64 + lane;
        double d = cen[t] - posd;
        double lg = -(d * d) / 10.0;
        double f = ((xw[t] == wv) ? 1.0 : 0.0) * ym * (double)mk[t];
        double masked = lg - (1.0 - f) * 1.0e9;
        float m32 = (float)masked;             // reference's astype(f32)
        ev[j] = m32;
        lmax = fmaxf(lmax, m32);
    }
    lmax = wmax_f(lmax);
    double lsum = 0.0;
#pragma unroll
    for (int j = 0; j < 8; j++) {
        float e = expf(__fsub_rn(ev[j], lmax));
        ev[j] = e;
        lsum += (double)e;
    }
    lsum = wsum_d(lsum);
    float tot = (float)lsum;
    float* wrow = outW + (size_t)r * TPH;
#pragma unroll
    for (int j = 0; j < 8; j++) {
        float w = __fdiv_rn(ev[j], tot);
        ev[j] = w;
        wrow[j * 64 + lane] = w;
    }
    // sparse attn: iterate nonzero weights in ascending t (ballot bits)
    double acc0 = 0.0, acc1 = 0.0, acc2 = 0.0, acc3 = 0.0;
    const float* xb = x + (size_t)b * TPH * HCH;
#pragma unroll
    for (int j = 0; j < 8; j++) {
        unsigned long long mball = __ballot(ev[j] > 0.f);
        while (mball) {
            int l2 = __ffsll(mball) - 1;
            mball &= mball - 1;
            float w = __shfl(ev[j], l2);
            int t = j * 64 + l2;
            float4 xv = ((const float4*)(xb + (size_t)t * HCH))[lane];
            acc0 += (double)w * (double)xv.x;
            acc1 += (double)w * (double)xv.y;
            acc2 += (double)w * (double)xv.z;
            acc3 += (double)w * (double)xv.w;
        }
    }
    float4 o;
    o.x = (float)acc0; o.y = (float)acc1; o.z = (float)acc2; o.w = (float)acc3;
    ((float4*)(outA + (size_t)r * HCH))[lane] = o;
}

extern "C" void kernel_launch(void* const* d_in, const int* in_sizes, int n_in,
                              void* d_out, int out_size, void* d_ws, size_t ws_size,
                              hipStream_t stream) {
    (void)in_sizes; (void)n_in; (void)out_size; (void)ws_size;
    const float* x    = (const float*)d_in[0];
    const float* xm   = (const float*)d_in[1];
    const float* pw1  = (const float*)d_in[2];
    const float* pb1  = (const float*)d_in[3];
    const float* g1   = (const float*)d_in[4];
    const float* be1  = (const float*)d_in[5];
    const float* pw2  = (const float*)d_in[6];
    const float* pb2  = (const float*)d_in[7];
    const float* g2   = (const float*)d_in[8];
    const float* be2  = (const float*)d_in[9];
    const float* pjw  = (const float*)d_in[10];
    const float* pjb  = (const float*)d_in[11];
    const float* gw   = (const float*)d_in[12];
    const float* gb   = (const float*)d_in[13];
    const int*   x2w  = (const int*)d_in[14];
    const int*   m2w  = (const int*)d_in[15];

    double* ws   = (double*)d_ws;
    double* wt1  = ws + OFF_WT1;
    double* wt2  = ws + OFF_WT2;
    double* h1   = ws + OFF_H1;
    double* h2   = ws + OFF_H2;
    double* mbuf = ws + OFF_M;
    double* cen  = ws + OFF_CEN;
    double* gvh  = ws + OFF_GVH;

    float* outA = (float*)d_out;
    float* outW = outA + (size_t)BATCH * TMEL * HCH;
    float* outM = outW + (size_t)BATCH * TMEL * TPH;

    hipMemsetAsync(h1, 0, (size_t)TMEL * HCH * sizeof(double), stream);
    hipMemsetAsync(h2, 0, (size_t)TMEL * HCH * sizeof(double), stream);
    hipLaunchKernelGGL(k_transpose_w, dim3(2 * KKTOT), dim3(256), 0, stream, pw1, pw2, wt1, wt2);
    hipLaunchKernelGGL(k_conv_gemm<float>, dim3(4, 64, 4), dim3(256), 0, stream, x, xm, wt1, h1);
    hipLaunchKernelGGL(k_ln_relu, dim3(4096), dim3(256), 0, stream, h1, pb1, g1, be1, h1);
    hipLaunchKernelGGL(k_conv_gemm<double>, dim3(4, 64, 4), dim3(256), 0, stream, h1, xm, wt2, h2);
    hipLaunchKernelGGL(k_ln_relu, dim3(4096), dim3(256), 0, stream, h2, pb2, g2, be2, h2);
    hipLaunchKernelGGL(k_gvh, dim3(1), dim3(256), 0, stream, gw, pjw, pjb, gvh);
    hipLaunchKernelGGL(k_m2, dim3(1024), dim3(256), 0, stream, x, h2, gw, gvh, gb, xm, mbuf);
    hipLaunchKernelGGL(k_dur, dim3(BATCH), dim3(512), 0, stream, mbuf, x2w, m2w, cen, outM);
    hipLaunchKernelGGL(k_attn, dim3(BATCH * TMEL / 4), dim3(256), 0, stream, x, cen, x2w, m2w, xm, outA, outW);
}

// Round 8
// 399.769 us; speedup vs baseline: 1.3048x; 1.3048x over previous
//
#include <hip/hip_runtime.h>
#include <math.h>

#define BATCH 8
#define TPH   512
#define TMEL  4096
#define HCH   256
#define WLEN  256
#define KKTOT 1280

// ws offsets (in doubles) — high-water 22.087 MB, proven safe in R3-R5
#define OFF_WT1 0          // 1280*256
#define OFF_WT2 327680     // 1280*256
#define OFF_H1  655360     // 4096*256
#define OFF_H2  1703936    // 4096*256
#define OFF_M   2752512    // 4096
#define OFF_CEN 2756608    // 4096
#define OFF_GVH 2760704    // 257
// conv2's 2nd split-K partial lives in d_out's outW region (consumed by ln2
// before k_attn overwrites outW).

// ---- wave (64-lane) reduction helpers ----
__device__ __forceinline__ double wsum_d(double v) {
#pragma unroll
    for (int o = 32; o > 0; o >>= 1) v += __shfl_xor(v, o);
    return v;
}
__device__ __forceinline__ float wmax_f(float v) {
#pragma unroll
    for (int o = 32; o > 0; o >>= 1) v = fmaxf(v, __shfl_xor(v, o));
    return v;
}

// transpose weights (O,I,K) -> (k*256+i, o), f32 -> f64
__global__ __launch_bounds__(256) void k_transpose_w(const float* __restrict__ w1,
                                                     const float* __restrict__ w2,
                                                     double* __restrict__ wt1,
                                                     double* __restrict__ wt2) {
    int idx = blockIdx.x;
    const float* src; double* dst; int kk;
    if (idx < KKTOT) { src = w1; dst = wt1; kk = idx; }
    else             { src = w2; dst = wt2; kk = idx - KKTOT; }
    int k = kk >> 8, i = kk & 255, o = threadIdx.x;
    dst[kk * HCH + o] = (double)src[o * KKTOT + i * 5 + k];
}

// f64 VALU conv-as-GEMM (R5-proven core): M=4096, N=256, K=1280.
// 64x64 tile, 4x4 micro, double-buffered LDS, skewed Bs (2-way free aliasing).
// Split-K x2 via blockIdx.z -> plain stores into separate partial buffers
// (p0/p1), summed deterministically in the LN kernel (no atomics).
template <typename TS>
__global__ __launch_bounds__(256) void k_conv_gemm(const TS* __restrict__ src,
                                                   const float* __restrict__ mask,
                                                   const double* __restrict__ wT,
                                                   double* __restrict__ p0,
                                                   double* __restrict__ p1) {
    __shared__ double As[2][16][66];
    __shared__ double Bs[2][16][70];
    int tid = threadIdx.x;
    int ty4 = (tid >> 4) * 4, tx4 = (tid & 15) * 4;
    int c0 = blockIdx.x * 64;
    int m0 = blockIdx.y * 64;
    int kb0 = blockIdx.z * 640;
    double* out = blockIdx.z ? p1 : p0;
    const int NT = 40;                   // 640 / 16

    // staging assignments
    int q4 = (tid & 3) * 4;      // A: k-quad within 16-k tile
    int m_l = tid >> 2;          // A: row 0..63
    int cB = tid & 63;           // B: col
    int kB0 = tid >> 6;          // B: k base (0..3), rows kB0+4j
    int pcB = cB + 2 * (cB >> 4);        // skewed B store col
    int ptx = tx4 + 2 * (tx4 >> 4);      // skewed B read col

    double acc[4][4];
#pragma unroll
    for (int i = 0; i < 4; i++)
#pragma unroll
        for (int j = 0; j < 4; j++) acc[i][j] = 0.0;

    int m = m0 + m_l;
    int mbase = m & ~511, mt = m & 511;

    double av[4], bv[4];

    auto fetch = [&](int kt) {
        int kb = kb0 + kt * 16;
        int kk = kb + q4;
        int k5 = kk >> 8, ci0 = kk & 255;
        int tt = mt + k5 - 2;
        if ((unsigned)tt < 512u) {
            int r = mbase + tt;
            double mk = (double)mask[r];
            const TS* sp = src + (size_t)r * HCH + ci0;
#pragma unroll
            for (int j = 0; j < 4; j++) av[j] = (double)sp[j] * mk;
        } else {
#pragma unroll
            for (int j = 0; j < 4; j++) av[j] = 0.0;
        }
        const double* wp = wT + (size_t)(kb + kB0) * HCH + c0 + cB;
#pragma unroll
        for (int j = 0; j < 4; j++) bv[j] = wp[(size_t)(j * 4) * HCH];
    };
    auto store = [&](int bf) {
#pragma unroll
        for (int j = 0; j < 4; j++) As[bf][q4 + j][m_l] = av[j];
#pragma unroll
        for (int j = 0; j < 4; j++) Bs[bf][kB0 + j * 4][pcB] = bv[j];
    };

    fetch(0);
    store(0);
    __syncthreads();
    int buf = 0;
    for (int kt = 0; kt < NT; kt++) {
        if (kt + 1 < NT) fetch(kt + 1);
#pragma unroll
        for (int k = 0; k < 16; k++) {
            const double2* Ap = (const double2*)&As[buf][k][ty4];
            const double2* Bp = (const double2*)&Bs[buf][k][ptx];
            double2 a01 = Ap[0], a23 = Ap[1];
            double2 b01 = Bp[0], b23 = Bp[1];
            double a[4] = {a01.x, a01.y, a23.x, a23.y};
            double bb[4] = {b01.x, b01.y, b23.x, b23.y};
#pragma unroll
            for (int i = 0; i < 4; i++)
#pragma unroll
                for (int j = 0; j < 4; j++) acc[i][j] += a[i] * bb[j];
        }
        if (kt + 1 < NT) store(buf ^ 1);
        __syncthreads();
        buf ^= 1;
    }
#pragma unroll
    for (int r = 0; r < 4; r++) {
        double* op = out + (size_t)(m0 + ty4 + r) * HCH + c0 + tx4;
#pragma unroll
        for (int j = 0; j < 4; j++) op[j] = acc[r][j];
    }
}

// f64: v = pa + pb + bias (deterministic split-K combine); channel-LN over 256; relu.
__global__ __launch_bounds__(256) void k_ln_relu(const double* __restrict__ pa,
                                                 const double* __restrict__ pb,
                                                 const float* __restrict__ bias,
                                                 const float* __restrict__ g,
                                                 const float* __restrict__ b,
                                                 double* __restrict__ out) {
    __shared__ double part[4];
    __shared__ double bc;
    int row = blockIdx.x, tid = threadIdx.x;
    int lane = tid & 63, wid = tid >> 6;
    double v = pa[row * HCH + tid] + pb[row * HCH + tid] + (double)bias[tid];
    double s = wsum_d(v);
    if (lane == 0) part[wid] = s;
    __syncthreads();
    if (tid == 0) bc = (part[0] + part[1] + part[2] + part[3]) * (1.0 / 256.0);
    __syncthreads();
    double mu = bc;
    double w = v - mu;
    s = wsum_d(w * w);
    if (lane == 0) part[wid] = s;
    __syncthreads();
    if (tid == 0) bc = (part[0] + part[1] + part[2] + part[3]) * (1.0 / 256.0);
    __syncthreads();
    double var = bc;
    double o = w * (1.0 / sqrt(var + 1e-4)) * (double)g[tid] + (double)b[tid];
    out[row * HCH + tid] = fmax(o, 0.0);
}

// gvh[i] = sum_c gw[c]*projw[c,i] (f64);  gvh[256] = sum_c gw[c]*projb[c]
__global__ __launch_bounds__(256) void k_gvh(const float* __restrict__ gw,
                                             const float* __restrict__ projw,
                                             const float* __restrict__ projb,
                                             double* __restrict__ gvh) {
    __shared__ double part[4];
    int i = threadIdx.x;
    int lane = i & 63, wid = i >> 6;
    double a0 = 0.0, a1 = 0.0, a2 = 0.0, a3 = 0.0;
    for (int c = 0; c < HCH; c += 4) {
        a0 += (double)gw[c + 0] * (double)projw[(c + 0) * HCH + i];
        a1 += (double)gw[c + 1] * (double)projw[(c + 1) * HCH + i];
        a2 += (double)gw[c + 2] * (double)projw[(c + 2) * HCH + i];
        a3 += (double)gw[c + 3] * (double)projw[(c + 3) * HCH + i];
    }
    gvh[i] = ((a0 + a1) + (a2 + a3));
    double s = wsum_d((double)gw[i] * (double)projb[i]);
    if (lane == 0) part[wid] = s;
    __syncthreads();
    if (i == 0) gvh[256] = part[0] + part[1] + part[2] + part[3];
}

// m[row] = (relu(mask*(<gw,x> + <gvh,h2> + gpb) + gb0) + 1) * mask   (one wave/row)
__global__ __launch_bounds__(256) void k_m2(const float* __restrict__ x,
                                            const double* __restrict__ h2,
                                            const float* __restrict__ gw,
                                            const double* __restrict__ gvh,
                                            const float* __restrict__ gb,
                                            const float* __restrict__ mask,
                                            double* __restrict__ mbuf) {
    int lane = threadIdx.x & 63;
    int row = blockIdx.x * 4 + (threadIdx.x >> 6);
    double acc = 0.0;
#pragma unroll
    for (int j = 0; j < 4; j++) {
        int c = j * 64 + lane;
        acc += (double)gw[c] * (double)x[row * HCH + c];
        acc += gvh[c] * h2[row * HCH + c];
    }
    acc = wsum_d(acc);
    if (lane == 0) {
        double mk = (double)mask[row];
        double g0 = mk * (acc + gvh[256]) + (double)gb[0];
        mbuf[row] = (fmax(g0, 0.0) + 1.0) * mk;
    }
}

// per-batch f64: deterministic dur scatter, mel counts, scale, parallel
// Hillis-Steele inclusive scan (f64 reassociation noise only) -> centers
__global__ __launch_bounds__(512) void k_dur(const double* __restrict__ mbuf,
                                             const int* __restrict__ x2w,
                                             const int* __restrict__ m2w,
                                             double* __restrict__ center,
                                             float* __restrict__ out_mword) {
    __shared__ double ms[512];
    __shared__ int xw[512];
    __shared__ double dur[257];
    __shared__ int cntw[257];
    __shared__ double sa[512], sb[512];
    int b = blockIdx.x, tid = threadIdx.x;
    if (tid < 257) cntw[tid] = 0;
    ms[tid] = mbuf[b * TPH + tid];
    {
        int w = x2w[b * TPH + tid];
        xw[tid] = max(0, min(256, w));
    }
    __syncthreads();
    for (int j = 0; j < TMEL / 512; j++) {
        int ww = m2w[b * TMEL + tid + j * 512];
        ww = max(0, min(256, ww));
        atomicAdd(&cntw[ww], 1);
    }
    __syncthreads();
    if (tid >= 1 && tid <= 256) {
        double s = 0.0;
        for (int t = 0; t < TPH; t++) {
            if (xw[t] == tid) s += ms[t];
        }
        dur[tid] = s;
        out_mword[b * WLEN + tid - 1] = (float)s;
    }
    __syncthreads();
    double msc;
    {
        int w = xw[tid];
        double sc = (double)cntw[w] / (dur[w] + 1e-4);
        msc = ms[tid] + (sc - 1.0) * ms[tid];
    }
    sa[tid] = msc;
    __syncthreads();
    // inclusive scan, 9 steps, ping-pong
    double* cur = sa; double* nxt = sb;
#pragma unroll
    for (int off = 1; off < 512; off <<= 1) {
        double v = cur[tid];
        if (tid >= off) v += cur[tid - off];
        nxt[tid] = v;
        __syncthreads();
        double* t = cur; cur = nxt; nxt = t;
    }
    center[b * TPH + tid] = cur[tid] - msc * 0.5;
}

// one WAVE per (b, mel) row: f64 logits, f32 cast at softmax input (the reference's
// astype), shuffle-only reductions (no LDS, no barriers), ballot-driven sparse attn.
__global__ __launch_bounds__(256) void k_attn(const float* __restrict__ x,
                                              const double* __restrict__ center,
                                              const int* __restrict__ x2w,
                                              const int* __restrict__ m2w,
                                              const float* __restrict__ mask,
                                              float* __restrict__ outA,
                                              float* __restrict__ outW) {
    int lane = threadIdx.x & 63, wid = threadIdx.x >> 6;
    int r = blockIdx.x * 4 + wid;              // r = b*4096 + mm
    int b = r >> 12;
    const double* cen = center + b * TPH;
    const int* xw = x2w + b * TPH;
    const float* mk = mask + b * TPH;
    int wv = m2w[r];
    double ym = (wv > 0) ? 1.0 : 0.0;
    double posd = (double)(r & 4095);
    float ev[8];
    float lmax = -3.0e38f;
#pragma unroll
    for (int j = 0; j < 8; j++) {
        int t = j * 64 + lane;
        double d = cen[t] - posd;
        double lg = -(d * d) / 10.0;
        double f = ((xw[t] == wv) ? 1.0 : 0.0) * ym * (double)mk[t];
        double masked = lg - (1.0 - f) * 1.0e9;
        float m32 = (float)masked;             // reference's astype(f32)
        ev[j] = m32;
        lmax = fmaxf(lmax, m32);
    }
    lmax = wmax_f(lmax);
    double lsum = 0.0;
#pragma unroll
    for (int j = 0; j < 8; j++) {
        float e = expf(__fsub_rn(ev[j], lmax));
        ev[j] = e;
        lsum += (double)e;
    }
    lsum = wsum_d(lsum);
    float tot = (float)lsum;
    float* wrow = outW + (size_t)r * TPH;
#pragma unroll
    for (int j = 0; j < 8; j++) {
        float w = __fdiv_rn(ev[j], tot);
        ev[j] = w;
        wrow[j * 64 + lane] = w;
    }
    // sparse attn: iterate nonzero weights in ascending t (ballot bits)
    double acc0 = 0.0, acc1 = 0.0, acc2 = 0.0, acc3 = 0.0;
    const float* xb = x + (size_t)b * TPH * HCH;
#pragma unroll
    for (int j = 0; j < 8; j++) {
        unsigned long long mball = __ballot(ev[j] > 0.f);
        while (mball) {
            int l2 = __ffsll(mball) - 1;
            mball &= mball - 1;
            float w = __shfl(ev[j], l2);
            int t = j * 64 + l2;
            float4 xv = ((const float4*)(xb + (size_t)t * HCH))[lane];
            acc0 += (double)w * (double)xv.x;
            acc1 += (double)w * (double)xv.y;
            acc2 += (double)w * (double)xv.z;
            acc3 += (double)w * (double)xv.w;
        }
    }
    float4 o;
    o.x = (float)acc0; o.y = (float)acc1; o.z = (float)acc2; o.w = (float)acc3;
    ((float4*)(outA + (size_t)r * HCH))[lane] = o;
}

extern "C" void kernel_launch(void* const* d_in, const int* in_sizes, int n_in,
                              void* d_out, int out_size, void* d_ws, size_t ws_size,
                              hipStream_t stream) {
    (void)in_sizes; (void)n_in; (void)out_size; (void)ws_size;
    const float* x    = (const float*)d_in[0];
    const float* xm   = (const float*)d_in[1];
    const float* pw1  = (const float*)d_in[2];
    const float* pb1  = (const float*)d_in[3];
    const float* g1   = (const float*)d_in[4];
    const float* be1  = (const float*)d_in[5];
    const float* pw2  = (const float*)d_in[6];
    const float* pb2  = (const float*)d_in[7];
    const float* g2   = (const float*)d_in[8];
    const float* be2  = (const float*)d_in[9];
    const float* pjw  = (const float*)d_in[10];
    const float* pjb  = (const float*)d_in[11];
    const float* gw   = (const float*)d_in[12];
    const float* gb   = (const float*)d_in[13];
    const int*   x2w  = (const int*)d_in[14];
    const int*   m2w  = (const int*)d_in[15];

    double* ws   = (double*)d_ws;
    double* wt1  = ws + OFF_WT1;
    double* wt2  = ws + OFF_WT2;
    double* h1   = ws + OFF_H1;
    double* h2   = ws + OFF_H2;
    double* mbuf = ws + OFF_M;
    double* cen  = ws + OFF_CEN;
    double* gvh  = ws + OFF_GVH;

    float* outA = (float*)d_out;
    float* outW = outA + (size_t)BATCH * TMEL * HCH;
    float* outM = outW + (size_t)BATCH * TMEL * TPH;
    // conv2's 2nd split-K partial: scratch inside outW (8 MB of its 67 MB),
    // fully consumed by ln2 before k_attn overwrites outW.
    double* pbuf = (double*)outW;

    hipLaunchKernelGGL(k_transpose_w, dim3(2 * KKTOT), dim3(256), 0, stream, pw1, pw2, wt1, wt2);
    // conv1: partials p0=h1, p1=h2 (h2 free here); ln1 sums -> h1
    hipLaunchKernelGGL(k_conv_gemm<float>, dim3(4, 64, 2), dim3(256), 0, stream, x, xm, wt1, h1, h2);
    hipLaunchKernelGGL(k_ln_relu, dim3(4096), dim3(256), 0, stream, h1, h2, pb1, g1, be1, h1);
    // conv2: partials p0=h2, p1=pbuf (in outW scratch); ln2 sums -> h2
    hipLaunchKernelGGL(k_conv_gemm<double>, dim3(4, 64, 2), dim3(256), 0, stream, h1, xm, wt2, h2, pbuf);
    hipLaunchKernelGGL(k_ln_relu, dim3(4096), dim3(256), 0, stream, h2, pbuf, pb2, g2, be2, h2);
    hipLaunchKernelGGL(k_gvh, dim3(1), dim3(256), 0, stream, gw, pjw, pjb, gvh);
    hipLaunchKernelGGL(k_m2, dim3(1024), dim3(256), 0, stream, x, h2, gw, gvh, gb, xm, mbuf);
    hipLaunchKernelGGL(k_dur, dim3(BATCH), dim3(512), 0, stream, mbuf, x2w, m2w, cen, outM);
    hipLaunchKernelGGL(k_attn, dim3(BATCH * TMEL / 4), dim3(256), 0, stream, x, cen, x2w, m2w, xm, outA, outW);
}

// Round 9
// 395.389 us; speedup vs baseline: 1.3193x; 1.0111x over previous
//
#include <hip/hip_runtime.h>
#include <math.h>

#define BATCH 8
#define TPH   512
#define TMEL  4096
#define HCH   256
#define WLEN  256
#define KKTOT 1280
#define PSZ   (TMEL * HCH)   // one split-K partial, in doubles

// ws offsets (in doubles) — high-water 22.087 MB, proven safe R3-R8
#define OFF_WT1 0          // 1280*256
#define OFF_WT2 327680     // 1280*256
#define OFF_H1  655360     // 4096*256
#define OFF_H2  1703936    // 4096*256
#define OFF_M   2752512    // 4096
#define OFF_CEN 2756608    // 4096
#define OFF_GVH 2760704    // 257
// conv split-K partials (8 x 8 MB = 64 MB) live in d_out's outW region
// (67.1 MB), fully consumed by the LN kernels before k_attn overwrites outW.

// ---- wave (64-lane) reduction helpers ----
__device__ __forceinline__ double wsum_d(double v) {
#pragma unroll
    for (int o = 32; o > 0; o >>= 1) v += __shfl_xor(v, o);
    return v;
}
__device__ __forceinline__ float wmax_f(float v) {
#pragma unroll
    for (int o = 32; o > 0; o >>= 1) v = fmaxf(v, __shfl_xor(v, o));
    return v;
}

// fused: blocks 0..2559 transpose weights (O,I,K)->(k*256+i,o) f32->f64;
// block 2560 computes gvh[i] = sum_c gw[c]*projw[c,i], gvh[256] = <gw,projb>
__global__ __launch_bounds__(256) void k_pre(const float* __restrict__ w1,
                                             const float* __restrict__ w2,
                                             double* __restrict__ wt1,
                                             double* __restrict__ wt2,
                                             const float* __restrict__ gw,
                                             const float* __restrict__ projw,
                                             const float* __restrict__ projb,
                                             double* __restrict__ gvh) {
    __shared__ double part[4];
    int idx = blockIdx.x;
    if (idx < 2 * KKTOT) {
        const float* src; double* dst; int kk;
        if (idx < KKTOT) { src = w1; dst = wt1; kk = idx; }
        else             { src = w2; dst = wt2; kk = idx - KKTOT; }
        int k = kk >> 8, i = kk & 255, o = threadIdx.x;
        dst[kk * HCH + o] = (double)src[o * KKTOT + i * 5 + k];
        return;
    }
    int i = threadIdx.x;
    int lane = i & 63, wid = i >> 6;
    double a0 = 0.0, a1 = 0.0, a2 = 0.0, a3 = 0.0;
    for (int c = 0; c < HCH; c += 4) {
        a0 += (double)gw[c + 0] * (double)projw[(c + 0) * HCH + i];
        a1 += (double)gw[c + 1] * (double)projw[(c + 1) * HCH + i];
        a2 += (double)gw[c + 2] * (double)projw[(c + 2) * HCH + i];
        a3 += (double)gw[c + 3] * (double)projw[(c + 3) * HCH + i];
    }
    gvh[i] = ((a0 + a1) + (a2 + a3));
    double s = wsum_d((double)gw[i] * (double)projb[i]);
    if (lane == 0) part[wid] = s;
    __syncthreads();
    if (i == 0) gvh[256] = part[0] + part[1] + part[2] + part[3];
}

// f64 conv-as-GEMM, LDS-read-minimized: 64-thread (1-wave) blocks, 64x64 tile,
// 8x8 micro (8 b128 LDS reads per 64 FMA — 2x fewer than 4x4), single LDS
// buffer (wave-internal barriers ~free), skewed As/Bs (10-stride groups ->
// 8 distinct addresses, 2-way free). Split-K x8 -> plain stores to partial z.
template <typename TS>
__global__ __launch_bounds__(64, 2) void k_conv_gemm(const TS* __restrict__ src,
                                                     const float* __restrict__ mask,
                                                     const double* __restrict__ wT,
                                                     double* __restrict__ pout) {
    __shared__ double As[16][78];
    __shared__ double Bs[16][78];
    int t = threadIdx.x;
    int c0 = blockIdx.x * 64;
    int m0 = blockIdx.y * 64;
    int kb0 = blockIdx.z * 160;
    double* out = pout + (size_t)blockIdx.z * PSZ;

    int m = m0 + t;
    int mbase = m & ~511, mt = m & 511;
    int kB = t >> 2, cq = (t & 3) * 16;      // B staging: row kB, cols cq..cq+15
    int scq = cq + 2 * (cq >> 3);            // skewed B store base
    int smt = t + 2 * (t >> 3);              // skewed A store col
    int ay = (t >> 3) * 10;                  // skewed A read base (8 rows)
    int by = (t & 7) * 10;                   // skewed B read base (8 cols)

    double acc[8][8];
#pragma unroll
    for (int i = 0; i < 8; i++)
#pragma unroll
        for (int j = 0; j < 8; j++) acc[i][j] = 0.0;

    for (int kt = 0; kt < 10; kt++) {
        int kb = kb0 + kt * 16;
        int k5 = kb >> 8, ci0 = kb & 255;    // all 16 kk share k5 (16-aligned)
        double av[16], bv[16];
        int tt = mt + k5 - 2;
        if ((unsigned)tt < 512u) {
            int r = mbase + tt;
            double mk = (double)mask[r];
            const TS* sp = src + (size_t)r * HCH + ci0;
#pragma unroll
            for (int k = 0; k < 16; k++) av[k] = (double)sp[k] * mk;
        } else {
#pragma unroll
            for (int k = 0; k < 16; k++) av[k] = 0.0;
        }
        {
            const double* wp = wT + (size_t)(kb + kB) * HCH + c0 + cq;
#pragma unroll
            for (int j = 0; j < 16; j++) bv[j] = wp[j];
        }
        __syncthreads();
#pragma unroll
        for (int k = 0; k < 16; k++) As[k][smt] = av[k];
#pragma unroll
        for (int j = 0; j < 16; j++) Bs[kB][scq + j + 2 * (j >> 3)] = bv[j];
        __syncthreads();
#pragma unroll
        for (int k = 0; k < 16; k++) {
            const double2* Ap = (const double2*)&As[k][ay];
            const double2* Bp = (const double2*)&Bs[k][by];
            double2 A0 = Ap[0], A1 = Ap[1], A2 = Ap[2], A3 = Ap[3];
            double2 B0 = Bp[0], B1 = Bp[1], B2 = Bp[2], B3 = Bp[3];
            double a[8] = {A0.x, A0.y, A1.x, A1.y, A2.x, A2.y, A3.x, A3.y};
            double b[8] = {B0.x, B0.y, B1.x, B1.y, B2.x, B2.y, B3.x, B3.y};
#pragma unroll
            for (int i = 0; i < 8; i++)
#pragma unroll
                for (int j = 0; j < 8; j++) acc[i][j] += a[i] * b[j];
        }
    }
#pragma unroll
    for (int i = 0; i < 8; i++) {
        double* op = out + (size_t)(m0 + (t >> 3) * 8 + i) * HCH + c0 + (t & 7) * 8;
#pragma unroll
        for (int j = 0; j < 8; j++) op[j] = acc[i][j];
    }
}

// f64: v = sum of 8 split-K partials + bias; channel-LN over 256; relu.
__global__ __launch_bounds__(256) void k_ln_relu(const double* __restrict__ p,
                                                 const float* __restrict__ bias,
                                                 const float* __restrict__ g,
                                                 const float* __restrict__ b,
                                                 double* __restrict__ out) {
    __shared__ double part[4];
    __shared__ double bc;
    int row = blockIdx.x, tid = threadIdx.x;
    int lane = tid & 63, wid = tid >> 6;
    size_t idx = (size_t)row * HCH + tid;
    double v = (double)bias[tid];
#pragma unroll
    for (int z = 0; z < 8; z++) v += p[(size_t)z * PSZ + idx];
    double s = wsum_d(v);
    if (lane == 0) part[wid] = s;
    __syncthreads();
    if (tid == 0) bc = (part[0] + part[1] + part[2] + part[3]) * (1.0 / 256.0);
    __syncthreads();
    double mu = bc;
    double w = v - mu;
    s = wsum_d(w * w);
    if (lane == 0) part[wid] = s;
    __syncthreads();
    if (tid == 0) bc = (part[0] + part[1] + part[2] + part[3]) * (1.0 / 256.0);
    __syncthreads();
    double var = bc;
    double o = w * (1.0 / sqrt(var + 1e-4)) * (double)g[tid] + (double)b[tid];
    out[idx] = fmax(o, 0.0);
}

// ln2 variant: also computes m[row] from the in-register h2 values
// (fuses old k_m2): m = (relu(mk*(<gw,x>+<gvh,h2>+gpb) + gb0) + 1) * mk
__global__ __launch_bounds__(256) void k_ln_relu_m(const double* __restrict__ p,
                                                   const float* __restrict__ bias,
                                                   const float* __restrict__ g,
                                                   const float* __restrict__ b,
                                                   double* __restrict__ out,
                                                   const float* __restrict__ x,
                                                   const float* __restrict__ gw,
                                                   const double* __restrict__ gvh,
                                                   const float* __restrict__ gb,
                                                   const float* __restrict__ mask,
                                                   double* __restrict__ mbuf) {
    __shared__ double part[4];
    __shared__ double bc;
    int row = blockIdx.x, tid = threadIdx.x;
    int lane = tid & 63, wid = tid >> 6;
    size_t idx = (size_t)row * HCH + tid;
    double v = (double)bias[tid];
#pragma unroll
    for (int z = 0; z < 8; z++) v += p[(size_t)z * PSZ + idx];
    double s = wsum_d(v);
    if (lane == 0) part[wid] = s;
    __syncthreads();
    if (tid == 0) bc = (part[0] + part[1] + part[2] + part[3]) * (1.0 / 256.0);
    __syncthreads();
    double mu = bc;
    double w = v - mu;
    s = wsum_d(w * w);
    if (lane == 0) part[wid] = s;
    __syncthreads();
    if (tid == 0) bc = (part[0] + part[1] + part[2] + part[3]) * (1.0 / 256.0);
    __syncthreads();
    double var = bc;
    double o = w * (1.0 / sqrt(var + 1e-4)) * (double)g[tid] + (double)b[tid];
    o = fmax(o, 0.0);
    out[idx] = o;
    // fused m-row reduction
    double red = gvh[tid] * o + (double)gw[tid] * (double)x[idx];
    s = wsum_d(red);
    if (lane == 0) part[wid] = s;
    __syncthreads();
    if (tid == 0) {
        double acc = part[0] + part[1] + part[2] + part[3];
        double mk = (double)mask[row];
        double g0 = mk * (acc + gvh[256]) + (double)gb[0];
        mbuf[row] = (fmax(g0, 0.0) + 1.0) * mk;
    }
}

// per-batch f64: deterministic dur scatter, mel counts, scale, parallel
// Hillis-Steele inclusive scan (f64 reassociation noise only) -> centers
__global__ __launch_bounds__(512) void k_dur(const double* __restrict__ mbuf,
                                             const int* __restrict__ x2w,
                                             const int* __restrict__ m2w,
                                             double* __restrict__ center,
                                             float* __restrict__ out_mword) {
    __shared__ double ms[512];
    __shared__ int xw[512];
    __shared__ double dur[257];
    __shared__ int cntw[257];
    __shared__ double sa[512], sb[512];
    int b = blockIdx.x, tid = threadIdx.x;
    if (tid < 257) cntw[tid] = 0;
    ms[tid] = mbuf[b * TPH + tid];
    {
        int w = x2w[b * TPH + tid];
        xw[tid] = max(0, min(256, w));
    }
    __syncthreads();
    for (int j = 0; j < TMEL / 512; j++) {
        int ww = m2w[b * TMEL + tid + j * 512];
        ww = max(0, min(256, ww));
        atomicAdd(&cntw[ww], 1);
    }
    __syncthreads();
    if (tid >= 1 && tid <= 256) {
        double s = 0.0;
        for (int t = 0; t < TPH; t++) {
            if (xw[t] == tid) s += ms[t];
        }
        dur[tid] = s;
        out_mword[b * WLEN + tid - 1] = (float)s;
    }
    __syncthreads();
    double msc;
    {
        int w = xw[tid];
        double sc = (double)cntw[w] / (dur[w] + 1e-4);
        msc = ms[tid] + (sc - 1.0) * ms[tid];
    }
    sa[tid] = msc;
    __syncthreads();
    double* cur = sa; double* nxt = sb;
#pragma unroll
    for (int off = 1; off < 512; off <<= 1) {
        double v = cur[tid];
        if (tid >= off) v += cur[tid - off];
        nxt[tid] = v;
        __syncthreads();
        double* tp = cur; cur = nxt; nxt = tp;
    }
    center[b * TPH + tid] = cur[tid] - msc * 0.5;
}

// one WAVE per (b, mel) row: f64 logits, f32 cast at softmax input (the reference's
// astype), shuffle-only reductions, ballot-driven sparse attn.
__global__ __launch_bounds__(256) void k_attn(const float* __restrict__ x,
                                              const double* __restrict__ center,
                                              const int* __restrict__ x2w,
                                              const int* __restrict__ m2w,
                                              const float* __restrict__ mask,
                                              float* __restrict__ outA,
                                              float* __restrict__ outW) {
    int lane = threadIdx.x & 63, wid = threadIdx.x >> 6;
    int r = blockIdx.x * 4 + wid;              // r = b*4096 + mm
    int b = r >> 12;
    const double* cen = center + b * TPH;
    const int* xw = x2w + b * TPH;
    const float* mk = mask + b * TPH;
    int wv = m2w[r];
    double ym = (wv > 0) ? 1.0 : 0.0;
    double posd = (double)(r & 4095);
    float ev[8];
    float lmax = -3.0e38f;
#pragma unroll
    for (int j = 0; j < 8; j++) {
        int t = j * 64 + lane;
        double d = cen[t] - posd;
        double lg = -(d * d) / 10.0;
        double f = ((xw[t] == wv) ? 1.0 : 0.0) * ym * (double)mk[t];
        double masked = lg - (1.0 - f) * 1.0e9;
        float m32 = (float)masked;             // reference's astype(f32)
        ev[j] = m32;
        lmax = fmaxf(lmax, m32);
    }
    lmax = wmax_f(lmax);
    double lsum = 0.0;
#pragma unroll
    for (int j = 0; j < 8; j++) {
        float e = expf(__fsub_rn(ev[j], lmax));
        ev[j] = e;
        lsum += (double)e;
    }
    lsum = wsum_d(lsum);
    float tot = (float)lsum;
    float* wrow = outW + (size_t)r * TPH;
#pragma unroll
    for (int j = 0; j < 8; j++) {
        float w = __fdiv_rn(ev[j], tot);
        ev[j] = w;
        wrow[j * 64 + lane] = w;
    }
    double acc0 = 0.0, acc1 = 0.0, acc2 = 0.0, acc3 = 0.0;
    const float* xb = x + (size_t)b * TPH * HCH;
#pragma unroll
    for (int j = 0; j < 8; j++) {
        unsigned long long mball = __ballot(ev[j] > 0.f);
        while (mball) {
            int l2 = __ffsll(mball) - 1;
            mball &= mball - 1;
            float w = __shfl(ev[j], l2);
            int t = j * 64 + l2;
            float4 xv = ((const float4*)(xb + (size_t)t * HCH))[lane];
            acc0 += (double)w * (double)xv.x;
            acc1 += (double)w * (double)xv.y;
            acc2 += (double)w * (double)xv.z;
            acc3 += (double)w * (double)xv.w;
        }
    }
    float4 o;
    o.x = (float)acc0; o.y = (float)acc1; o.z = (float)acc2; o.w = (float)acc3;
    ((float4*)(outA + (size_t)r * HCH))[lane] = o;
}

extern "C" void kernel_launch(void* const* d_in, const int* in_sizes, int n_in,
                              void* d_out, int out_size, void* d_ws, size_t ws_size,
                              hipStream_t stream) {
    (void)in_sizes; (void)n_in; (void)out_size; (void)ws_size;
    const float* x    = (const float*)d_in[0];
    const float* xm   = (const float*)d_in[1];
    const float* pw1  = (const float*)d_in[2];
    const float* pb1  = (const float*)d_in[3];
    const float* g1   = (const float*)d_in[4];
    const float* be1  = (const float*)d_in[5];
    const float* pw2  = (const float*)d_in[6];
    const float* pb2  = (const float*)d_in[7];
    const float* g2   = (const float*)d_in[8];
    const float* be2  = (const float*)d_in[9];
    const float* pjw  = (const float*)d_in[10];
    const float* pjb  = (const float*)d_in[11];
    const float* gw   = (const float*)d_in[12];
    const float* gb   = (const float*)d_in[13];
    const int*   x2w  = (const int*)d_in[14];
    const int*   m2w  = (const int*)d_in[15];

    double* ws   = (double*)d_ws;
    double* wt1  = ws + OFF_WT1;
    double* wt2  = ws + OFF_WT2;
    double* h1   = ws + OFF_H1;
    double* h2   = ws + OFF_H2;
    double* mbuf = ws + OFF_M;
    double* cen  = ws + OFF_CEN;
    double* gvh  = ws + OFF_GVH;

    float* outA = (float*)d_out;
    float* outW = outA + (size_t)BATCH * TMEL * HCH;
    float* outM = outW + (size_t)BATCH * TMEL * TPH;
    // split-K partials: 8 x 8 MB in outW scratch (67.1 MB), consumed by the LN
    // kernels before k_dur/k_attn write outM/outW.
    double* pbuf = (double*)outW;

    hipLaunchKernelGGL(k_pre, dim3(2 * KKTOT + 1), dim3(256), 0, stream,
                       pw1, pw2, wt1, wt2, gw, pjw, pjb, gvh);
    hipLaunchKernelGGL(k_conv_gemm<float>, dim3(4, 64, 8), dim3(64), 0, stream, x, xm, wt1, pbuf);
    hipLaunchKernelGGL(k_ln_relu, dim3(4096), dim3(256), 0, stream, pbuf, pb1, g1, be1, h1);
    hipLaunchKernelGGL(k_conv_gemm<double>, dim3(4, 64, 8), dim3(64), 0, stream, h1, xm, wt2, pbuf);
    hipLaunchKernelGGL(k_ln_relu_m, dim3(4096), dim3(256), 0, stream, pbuf, pb2, g2, be2, h2,
                       x, gw, gvh, gb, xm, mbuf);
    hipLaunchKernelGGL(k_dur, dim3(BATCH), dim3(512), 0, stream, mbuf, x2w, m2w, cen, outM);
    hipLaunchKernelGGL(k_attn, dim3(BATCH * TMEL / 4), dim3(256), 0, stream, x, cen, x2w, m2w, xm, outA, outW);
}